// Round 3
// baseline (690.326 us; speedup 1.0000x reference)
//
#include <hip/hip_runtime.h>

#define S_LEN 1024
#define HIDN  4096
#define NH    64
#define HD    64
#define NCH   32     // chunks
#define CLEN  32     // steps per chunk

typedef short bf16x8 __attribute__((ext_vector_type(8)));
typedef float f32x4  __attribute__((ext_vector_type(4)));

__device__ __forceinline__ unsigned short f2bf(float x){
  unsigned u = __float_as_uint(x);
  u += 0x7fffu + ((u >> 16) & 1u);   // round-to-nearest-even
  return (unsigned short)(u >> 16);
}

__device__ __forceinline__ void gload_lds16(const void* g, void* l){
  __builtin_amdgcn_global_load_lds(
      (const __attribute__((address_space(1))) void*)g,
      (__attribute__((address_space(3))) void*)l, 16, 0, 0);
}

// sched_barrier(0) ONLY at barriers: pins phase boundaries (reads can't hoist
// above the barrier that publishes staged LDS; MFMAs can't sink out of their
// phase) while leaving the INTERIOR free for the compiler's fine-grained
// lgkmcnt(N) ds_read<->MFMA interleave (m141 lesson: pinning the interior
// serialized LDS drain and MFMA -> 31% MfmaUtil in R1).
#define SBAR() do { __builtin_amdgcn_sched_barrier(0); \
                    __builtin_amdgcn_s_barrier();      \
                    __builtin_amdgcn_sched_barrier(0); } while(0)
#define WAIT_VM4()  do { asm volatile("s_waitcnt vmcnt(4)" ::: "memory"); } while(0)
#define WAIT_VM0()  do { asm volatile("s_waitcnt vmcnt(0)" ::: "memory"); } while(0)

// ------------- weight pre-convert: 5 x [4096][4096] fp32 -> bf16 -------------
__global__ __launch_bounds__(256)
void wconv_kernel(const float* __restrict__ w0, const float* __restrict__ w1,
                  const float* __restrict__ w2, const float* __restrict__ w3,
                  const float* __restrict__ w4, unsigned short* __restrict__ out)
{
  const int z = blockIdx.y;
  const float* __restrict__ w = (z==0)?w0:(z==1)?w1:(z==2)?w2:(z==3)?w3:w4;
  const size_t idx = (size_t)blockIdx.x * 2048 + (size_t)threadIdx.x * 8;
  float4 a = *(const float4*)(w + idx);
  float4 b = *(const float4*)(w + idx + 4);
  ushort4 lo, hi;
  lo.x = f2bf(a.x); lo.y = f2bf(a.y); lo.z = f2bf(a.z); lo.w = f2bf(a.w);
  hi.x = f2bf(b.x); hi.y = f2bf(b.y); hi.z = f2bf(b.z); hi.w = f2bf(b.w);
  unsigned short* o = out + (size_t)z * HIDN * HIDN + idx;
  *(ushort4*)(o)     = lo;
  *(ushort4*)(o + 4) = hi;
}

// ---------------- token-mix prepass: mixed[z][s][i] (bf16) -------------------
__global__ __launch_bounds__(256)
void mix_kernel(const float* __restrict__ hidden,
                const float* __restrict__ tmk, const float* __restrict__ tmv,
                const float* __restrict__ tmr, const float* __restrict__ tmg,
                unsigned short* __restrict__ mixed)
{
  int idx = blockIdx.x * 256 + threadIdx.x;      // 0 .. S*HID-1
  int i = idx & (HIDN - 1);
  float h  = hidden[idx];
  float sh = (idx >= HIDN) ? hidden[idx - HIDN] : 0.f;
  float mk = tmk[i], mv = tmv[i], mr = tmr[i], mg = tmg[i];
  mixed[idx + 0 * S_LEN * HIDN] = f2bf(h * mk + sh * (1.f - mk));
  mixed[idx + 1 * S_LEN * HIDN] = f2bf(h * mv + sh * (1.f - mv));
  mixed[idx + 2 * S_LEN * HIDN] = f2bf(h * mr + sh * (1.f - mr));
  mixed[idx + 3 * S_LEN * HIDN] = f2bf(h * mg + sh * (1.f - mg));
}

// --------- 256x256 pipelined GEMM body: C = A(256xK) @ W(256xK)^T ------------
// 4 phases/K-tile, 16 MFMA/phase, 1 barrier/phase. Counted vmcnt(4) once per
// K-tile AFTER P4's MFMA (MFMA covers residual vmem latency). Interior is
// unpinned: compiler emits fine-grained lgkmcnt(N) so the LDS-read drain
// overlaps the MFMA stream. XOR swizzle byte^=(row&7)<<4 via pre-swizzled
// global source + swizzled ds_read (gload_lds dest stays linear).
// Slot liveness (1 barrier/phase):
//   As[dbA] last read T-1 P3, overwrite issued T P1  -> 2 barriers apart.
//   Bs[db]  last read T   P2, overwrite issued T P3  -> 1 barrier apart.
//   Staged-data visibility: per-wave vmcnt(4) + tile-boundary barrier.
template<int KTILES, bool ATOMIC>
__device__ __forceinline__ void gemm_body(
    const unsigned short* __restrict__ A, const unsigned short* __restrict__ W,
    float* __restrict__ C, int m0, int n0, int kbase, bool do_silu)
{
  __shared__ __align__(16) unsigned short As[2][2][128 * 64];  // [db][half]
  __shared__ __align__(16) unsigned short Bs[2][2][128 * 64];

  const int tid  = threadIdx.x;
  const int lane = tid & 63;
  const int wid  = tid >> 6;
  const int wr   = wid >> 2;          // 0..1  M-half of the wave
  const int wc   = wid & 3;           // 0..3  N-quarter of the wave
  const int fr   = lane & 15;
  const int fku  = lane >> 4;         // 0..3
  const int cxA  = fku * 16;          // byte col base within a 128B LDS row

  // staging: thread covers 2x16B of each 128x64 half-tile (16 KB).
  const int ob0 = tid * 16, ob1 = (512 + tid) * 16;
  const int r0 = ob0 >> 7, r1 = ob1 >> 7;                 // 0..63 / 64..127
  const int cb0 = (ob0 & 127) ^ ((r0 & 7) << 4);
  const int cb1 = (ob1 & 127) ^ ((r1 & 7) << 4);
  const unsigned short* A0 = A + (size_t)(m0 + r0) * HIDN + kbase + (cb0 >> 1);
  const unsigned short* A1 = A + (size_t)(m0 + r1) * HIDN + kbase + (cb1 >> 1);
  const unsigned short* W0 = W + (size_t)(n0 + r0) * HIDN + kbase + (cb0 >> 1);
  const unsigned short* W1 = W + (size_t)(n0 + r1) * HIDN + kbase + (cb1 >> 1);
  const int lo0 = ob0 >> 1, lo1 = ob1 >> 1;               // ushort offsets

  f32x4 acc[8][4];
#pragma unroll
  for (int mi = 0; mi < 8; ++mi)
#pragma unroll
    for (int ni = 0; ni < 4; ++ni) acc[mi][ni] = (f32x4){0.f, 0.f, 0.f, 0.f};

  auto stageA = [&](int t, int h, int db) {
    gload_lds16(A0 + (size_t)h * 128 * HIDN + t * 64, &As[db][h][lo0]);
    gload_lds16(A1 + (size_t)h * 128 * HIDN + t * 64, &As[db][h][lo1]);
  };
  auto stageB = [&](int t, int h, int db) {
    gload_lds16(W0 + (size_t)h * 128 * HIDN + t * 64, &Bs[db][h][lo0]);
    gload_lds16(W1 + (size_t)h * 128 * HIDN + t * 64, &Bs[db][h][lo1]);
  };
  auto readA = [&](bf16x8 (&a)[2][4], int db, int mh) {
#pragma unroll
    for (int kk = 0; kk < 2; ++kk)
#pragma unroll
      for (int mi = 0; mi < 4; ++mi) {
        int rr  = mh * 64 + mi * 16 + fr;
        int byo = rr * 128 + ((kk * 64 + cxA) ^ ((rr & 7) << 4));
        a[kk][mi] = *(const bf16x8*)((const char*)As[db][wr] + byo);
      }
  };
  auto readB = [&](bf16x8 (&b)[2][2], int db, int nh) {
#pragma unroll
    for (int kk = 0; kk < 2; ++kk)
#pragma unroll
      for (int ni = 0; ni < 2; ++ni) {
        int rr  = (wc & 1) * 64 + nh * 32 + ni * 16 + fr;
        int byo = rr * 128 + ((kk * 64 + cxA) ^ ((rr & 7) << 4));
        b[kk][ni] = *(const bf16x8*)((const char*)Bs[db][wc >> 1] + byo);
      }
  };
  auto quad = [&](bf16x8 (&a)[2][4], bf16x8 (&b)[2][2], int mh, int nh) {
#pragma unroll
    for (int kk = 0; kk < 2; ++kk)
#pragma unroll
      for (int mi = 0; mi < 4; ++mi)
#pragma unroll
        for (int ni = 0; ni < 2; ++ni)
          acc[mh * 4 + mi][nh * 2 + ni] = __builtin_amdgcn_mfma_f32_16x16x32_bf16(
              a[kk][mi], b[kk][ni], acc[mh * 4 + mi][nh * 2 + ni], 0, 0, 0);
  };

  // prologue: B(0), A(0) into slot 0; B(1) into slot 1. vmcnt(4) leaves the
  // two B(1) halves in flight, guarantees tile 0 fully staged.
  stageB(0, 0, 0); stageB(0, 1, 0);
  stageA(0, 0, 0); stageA(0, 1, 0);
  stageB(1, 0, 1); stageB(1, 1, 1);
  WAIT_VM4();
  SBAR();

  bf16x8 a8[2][4], b0[2][2], b1[2][2];

  for (int T = 0; T < KTILES; ++T) {
    const int db  = T & 1;
    const int dbA = db ^ 1;
    const int tA  = (T + 1 < KTILES) ? T + 1 : T;   // tail: harmless re-stage
    const int tB  = (T + 2 < KTILES) ? T + 2 : T;
    // ---- P1: reads A[mh=0](8) + B[nh=0](4); stage A(T+1)h0; quad(0,0) ----
    readA(a8, db, 0);
    readB(b0, db, 0);
    stageA(tA, 0, dbA);
    __builtin_amdgcn_s_setprio(1);
    quad(a8, b0, 0, 0);
    __builtin_amdgcn_s_setprio(0);
    SBAR();
    // ---- P2: reads B[nh=1](4); stage A(T+1)h1; quad(0,1) ----
    readB(b1, db, 1);
    stageA(tA, 1, dbA);
    __builtin_amdgcn_s_setprio(1);
    quad(a8, b1, 0, 1);
    __builtin_amdgcn_s_setprio(0);
    SBAR();
    // ---- P3: reads A[mh=1](8); stage B(T+2)h0; quad(1,1) ----
    readA(a8, db, 1);
    stageB(tB, 0, db);
    __builtin_amdgcn_s_setprio(1);
    quad(a8, b1, 1, 1);
    __builtin_amdgcn_s_setprio(0);
    SBAR();
    // ---- P4: no reads; stage B(T+2)h1; quad(1,0); counted vmcnt ----
    stageB(tB, 1, db);
    __builtin_amdgcn_s_setprio(1);
    quad(a8, b0, 1, 0);
    __builtin_amdgcn_s_setprio(0);
    WAIT_VM4();
    SBAR();
  }
  WAIT_VM0();   // drain leftover (garbage) prefetch before epilogue

  const int orow = fku * 4;
#pragma unroll
  for (int mi = 0; mi < 8; ++mi)
#pragma unroll
    for (int ni = 0; ni < 4; ++ni)
#pragma unroll
      for (int r = 0; r < 4; ++r) {
        int row = m0 + wr * 128 + mi * 16 + orow + r;
        int col = n0 + wc * 64 + ni * 16 + fr;
        float v = acc[mi][ni][r];
        if (ATOMIC) {
          atomicAdd(&C[(size_t)row * HIDN + col], v);
        } else {
          if (do_silu) v = v / (1.f + __expf(-v));
          C[(size_t)row * HIDN + col] = v;
        }
      }
}

// k,v,r,g projections: grid 256 = 4z x 16nt x 4mt; full K=4096 (64 K-tiles).
__global__ __launch_bounds__(512, 2)
void gemm_main(const unsigned short* __restrict__ Aall,
               const unsigned short* __restrict__ Wall,
               float* __restrict__ Call, int silu_mask)
{
  const int bid  = blockIdx.x;
  const int xcd  = bid & 7;
  const int slot = bid >> 3;                 // 0..31
  const int nz   = xcd * 8 + (slot >> 2);    // 0..63
  const int mt   = slot & 3;
  const int z    = nz >> 4;
  const int nt   = nz & 15;
  gemm_body<64, false>(Aall + (size_t)z * S_LEN * HIDN,
                       Wall + (size_t)z * HIDN * HIDN,
                       Call + (size_t)z * S_LEN * HIDN,
                       mt * 256, nt * 256, 0, (silu_mask >> z) & 1);
}

// output projection: split-K x4, grid 256 = 8xcd x {nt-lo, ks(2b), mt(2b)}.
// Blocks sharing a (nt,ks) W-chunk (the 4 mts) sit on one XCD. atomicAdd
// epilogue (4 writers/address), C zeroed first.
__global__ __launch_bounds__(512, 2)
void gemm_out(const unsigned short* __restrict__ A,
              const unsigned short* __restrict__ W,
              float* __restrict__ C)
{
  const int bid  = blockIdx.x;
  const int xcd  = bid & 7;
  const int slot = bid >> 3;                 // 0..31
  const int nt   = xcd * 2 + (slot & 1);     // 0..15
  const int ks   = (slot >> 1) & 3;          // 0..3
  const int mt   = (slot >> 3) & 3;          // 0..3
  gemm_body<16, true>(A, W, C, mt * 256, nt * 256, ks * (HIDN / 4), false);
}

// -------------------- recurrence pass 1: local chunk states ------------------
__global__ __launch_bounds__(64)
void rec_pass1(const float* __restrict__ kb, const float* __restrict__ vb,
               const float* __restrict__ time_decay, float* __restrict__ X)
{
  const int c = blockIdx.x, h = blockIdx.y, e = threadIdx.x;
  const float tde = __expf(-__expf(time_decay[h * 64 + e]));
  float td[64];
#pragma unroll
  for (int d = 0; d < 64; ++d) td[d] = __shfl(tde, d, 64);
  float st[64];
#pragma unroll
  for (int d = 0; d < 64; ++d) st[d] = 0.f;

  for (int t = c * CLEN; t < c * CLEN + CLEN; ++t) {
    const size_t off = (size_t)t * HIDN + h * 64;
    const float vl = vb[off + e];
    const float* __restrict__ krow = kb + off;   // uniform address over d
#pragma unroll
    for (int d = 0; d < 64; ++d)
      st[d] = fmaf(td[d], st[d], krow[d] * vl);
  }
#pragma unroll
  for (int d = 0; d < 64; ++d)
    X[(((size_t)c * NH + h) * 64 + d) * 64 + e] = st[d];
}

// ------------- recurrence pass 2: scan boundary states across chunks ---------
__global__ __launch_bounds__(64)
void rec_pass2(const float* __restrict__ time_decay,
               const float* __restrict__ X, float* __restrict__ Y)
{
  const int h = blockIdx.x, dq = blockIdx.y, e = threadIdx.x;
  float tdc[16];
#pragma unroll
  for (int i = 0; i < 16; ++i)
    tdc[i] = __expf(-(float)CLEN * __expf(time_decay[h * 64 + dq * 16 + i]));
  float acc[16];
#pragma unroll
  for (int i = 0; i < 16; ++i) acc[i] = 0.f;
  for (int c = 0; c < NCH; ++c) {
#pragma unroll
    for (int i = 0; i < 16; ++i) {
      size_t idx = (((size_t)c * NH + h) * 64 + dq * 16 + i) * 64 + e;
      Y[idx] = acc[i];
      acc[i] = fmaf(tdc[i], acc[i], X[idx]);
    }
  }
}

// ------- recurrence pass 3: outputs + fused GroupNorm + gate -> A2 (bf16) ----
__global__ __launch_bounds__(64)
void rec_pass3(const float* __restrict__ kb, const float* __restrict__ vb,
               const float* __restrict__ rb, const float* __restrict__ gb,
               const float* __restrict__ time_decay, const float* __restrict__ time_faaaa,
               const float* __restrict__ gnw, const float* __restrict__ gnb,
               const float* __restrict__ Y, unsigned short* __restrict__ A2)
{
  const int c = blockIdx.x, h = blockIdx.y, e = threadIdx.x;
  const float tde = __expf(-__expf(time_decay[h * 64 + e]));
  float td[64];
#pragma unroll
  for (int d = 0; d < 64; ++d) td[d] = __shfl(tde, d, 64);
  float st[64];
#pragma unroll
  for (int d = 0; d < 64; ++d)
    st[d] = Y[(((size_t)c * NH + h) * 64 + d) * 64 + e];

  const float tf_l  = time_faaaa[h * 64 + e];
  const float gnw_l = gnw[h * 64 + e];
  const float gnb_l = gnb[h * 64 + e];

  for (int t = c * CLEN; t < c * CLEN + CLEN; ++t) {
    const size_t off = (size_t)t * HIDN + h * 64;
    const float kl = kb[off + e], rl = rb[off + e];
    const float vl = vb[off + e], gl = gb[off + e];

    float Asum = rl * tf_l * kl;
#pragma unroll
    for (int i = 1; i < 64; i <<= 1) Asum += __shfl_xor(Asum, i, 64);

    const float* __restrict__ krow = kb + off;   // uniform address over d
    const float* __restrict__ rrow = rb + off;
    float dot = 0.f;
#pragma unroll
    for (int d = 0; d < 64; ++d) {
      dot   = fmaf(rrow[d], st[d], dot);                 // uses state_{t-1}
      st[d] = fmaf(td[d], st[d], krow[d] * vl);          // state_t
    }
    float o = fmaf(Asum, vl, dot);

    float s1 = o, s2 = o * o;
#pragma unroll
    for (int i = 1; i < 64; i <<= 1) {
      s1 += __shfl_xor(s1, i, 64);
      s2 += __shfl_xor(s2, i, 64);
    }
    float mean = s1 * (1.f / 64.f);
    float var  = s2 * (1.f / 64.f) - mean * mean;
    float xn   = (o - mean) * rsqrtf(var + 1e-5f);
    float yv   = xn * gnw_l + gnb_l;
    A2[off + e] = f2bf(gl * yv);
  }
}

// -----------------------------------------------------------------------------
extern "C" void kernel_launch(void* const* d_in, const int* in_sizes, int n_in,
                              void* d_out, int out_size, void* d_ws, size_t ws_size,
                              hipStream_t stream)
{
  const float* hidden     = (const float*)d_in[0];
  const float* w_key      = (const float*)d_in[1];
  const float* w_value    = (const float*)d_in[2];
  const float* w_recep    = (const float*)d_in[3];
  const float* w_gate     = (const float*)d_in[4];
  const float* w_output   = (const float*)d_in[5];
  const float* tmk        = (const float*)d_in[6];
  const float* tmv        = (const float*)d_in[7];
  const float* tmr        = (const float*)d_in[8];
  const float* tmg        = (const float*)d_in[9];
  const float* time_decay = (const float*)d_in[10];
  const float* time_faaaa = (const float*)d_in[11];
  const float* gnw        = (const float*)d_in[12];
  const float* gnb        = (const float*)d_in[13];
  float* out = (float*)d_out;

  char* ws = (char*)d_ws;
  // ws layout (bytes):
  //   wbf   bf16 [5][4096][4096]  @ 0          (167,772,160)  wk,wv,wr,wg,wo
  //     Y   f32  [32][64][64][64] @ 0          (33,554,432)   aliases wk+wv (dead after gemms)
  //   mixed bf16 [4][S][HID]      @ 167772160  (33,554,432)
  //     X   f32  [32][64][64][64] @ 167772160  aliases mixed  (dead after gemms)
  //   kvrg  f32  [4][S][HID]      @ 201326592  (67,108,864)
  //   A2    bf16 [S][HID]         @ 268435456  (8,388,608)    total 276.8 MB
  unsigned short* wbf   = (unsigned short*)(ws);
  float*          Y     = (float*)(ws);
  unsigned short* mixed = (unsigned short*)(ws + 167772160);
  float*          X     = (float*)(ws + 167772160);
  float*          kvrg  = (float*)(ws + 201326592);
  unsigned short* A2    = (unsigned short*)(ws + 268435456);

  const float* kb = kvrg + 0 * (size_t)S_LEN * HIDN;
  const float* vb = kvrg + 1 * (size_t)S_LEN * HIDN;
  const float* rb = kvrg + 2 * (size_t)S_LEN * HIDN;
  const float* gb = kvrg + 3 * (size_t)S_LEN * HIDN;

  wconv_kernel<<<dim3(HIDN * HIDN / 2048, 5), 256, 0, stream>>>(
      w_key, w_value, w_recep, w_gate, w_output, wbf);

  mix_kernel<<<dim3(S_LEN * HIDN / 256), 256, 0, stream>>>(hidden, tmk, tmv, tmr, tmg, mixed);

  // k,v,r,g = mixed[z] @ W[z]^T ; silu on z==3 (gate). 256 blocks, 512 thr.
  gemm_main<<<dim3(256), 512, 0, stream>>>(mixed, wbf, kvrg, 0x8);

  rec_pass1<<<dim3(NCH, NH), 64, 0, stream>>>(kb, vb, time_decay, X);
  rec_pass2<<<dim3(NH, 4), 64, 0, stream>>>(time_decay, X, Y);
  rec_pass3<<<dim3(NCH, NH), 64, 0, stream>>>(kb, vb, rb, gb, time_decay, time_faaaa,
                                              gnw, gnb, Y, A2);

  // out = (g * groupnorm(o)) @ w_output^T, split-K x4 with atomic epilogue.
  hipMemsetAsync(d_out, 0, (size_t)out_size * sizeof(float), stream);
  gemm_out<<<dim3(256), 512, 0, stream>>>(A2, wbf + 4 * (size_t)HIDN * HIDN, out);
}

// Round 4
// 638.100 us; speedup vs baseline: 1.0818x; 1.0818x over previous
//
#include <hip/hip_runtime.h>

#define S_LEN 1024
#define HIDN  4096
#define NH    64
#define HD    64
#define NCH   32     // chunks
#define CLEN  32     // steps per chunk

typedef short bf16x8 __attribute__((ext_vector_type(8)));
typedef float f32x4  __attribute__((ext_vector_type(4)));

__device__ __forceinline__ unsigned short f2bf(float x){
  unsigned u = __float_as_uint(x);
  u += 0x7fffu + ((u >> 16) & 1u);   // round-to-nearest-even
  return (unsigned short)(u >> 16);
}

__device__ __forceinline__ void gload_lds16(const void* g, void* l){
  __builtin_amdgcn_global_load_lds(
      (const __attribute__((address_space(1))) void*)g,
      (__attribute__((address_space(3))) void*)l, 16, 0, 0);
}

#define BAR() __builtin_amdgcn_s_barrier()
#define WAIT_VM4()  do { asm volatile("s_waitcnt vmcnt(4)" ::: "memory"); } while(0)
#define WAIT_VM0()  do { asm volatile("s_waitcnt vmcnt(0)" ::: "memory"); } while(0)

// ------------- weight pre-convert: 5 x [4096][4096] fp32 -> bf16 -------------
__global__ __launch_bounds__(256)
void wconv_kernel(const float* __restrict__ w0, const float* __restrict__ w1,
                  const float* __restrict__ w2, const float* __restrict__ w3,
                  const float* __restrict__ w4, unsigned short* __restrict__ out)
{
  const int z = blockIdx.y;
  const float* __restrict__ w = (z==0)?w0:(z==1)?w1:(z==2)?w2:(z==3)?w3:w4;
  const size_t idx = (size_t)blockIdx.x * 2048 + (size_t)threadIdx.x * 8;
  float4 a = *(const float4*)(w + idx);
  float4 b = *(const float4*)(w + idx + 4);
  ushort4 lo, hi;
  lo.x = f2bf(a.x); lo.y = f2bf(a.y); lo.z = f2bf(a.z); lo.w = f2bf(a.w);
  hi.x = f2bf(b.x); hi.y = f2bf(b.y); hi.z = f2bf(b.z); hi.w = f2bf(b.w);
  unsigned short* o = out + (size_t)z * HIDN * HIDN + idx;
  *(ushort4*)(o)     = lo;
  *(ushort4*)(o + 4) = hi;
}

// ---------------- token-mix prepass: mixed[z][s][i] (bf16) -------------------
__global__ __launch_bounds__(256)
void mix_kernel(const float* __restrict__ hidden,
                const float* __restrict__ tmk, const float* __restrict__ tmv,
                const float* __restrict__ tmr, const float* __restrict__ tmg,
                unsigned short* __restrict__ mixed)
{
  int idx = blockIdx.x * 256 + threadIdx.x;      // 0 .. S*HID-1
  int i = idx & (HIDN - 1);
  float h  = hidden[idx];
  float sh = (idx >= HIDN) ? hidden[idx - HIDN] : 0.f;
  float mk = tmk[i], mv = tmv[i], mr = tmr[i], mg = tmg[i];
  mixed[idx + 0 * S_LEN * HIDN] = f2bf(h * mk + sh * (1.f - mk));
  mixed[idx + 1 * S_LEN * HIDN] = f2bf(h * mv + sh * (1.f - mv));
  mixed[idx + 2 * S_LEN * HIDN] = f2bf(h * mr + sh * (1.f - mr));
  mixed[idx + 3 * S_LEN * HIDN] = f2bf(h * mg + sh * (1.f - mg));
}

// --------- 256x256 pipelined GEMM body: C = A(256xK) @ W(256xK)^T ------------
// SW-pipelined fragment reads (one window ahead) + 2 barriers/K-tile.
// Windows per K-tile (16 MFMA each):
//   tail(T-1): vmcnt(4); BAR; read a0(T),b0(T)     <- publication-safe
//   W1: read b1(T) | stage A(T+1)h0 | Q1 = a0*b0
//   W2: stage A(T+1)h1 | Q2 = a0*b1 ; read a1(T) (reg-reuse after Q2)
//   MIDBAR   (separates other waves' b-reads from the B-stage WAR)
//   W3: stage B(T+2)h0 | Q3 = a1*b1
//   W4: stage B(T+2)h1 | Q4 = a1*b0 ; vmcnt(4); BAR; tail reads
// Every fragment read except the 12 boundary reads drains under an MFMA
// cluster (cross-window overlap). No manual lgkm waits: reads are plain C++
// loads, compiler emits fine-grained lgkmcnt(N) (near-optimal per guide).
// Liveness: As[dbA] stage (W1/W2 of T) vs its last reads (a1, W2 of T-1):
// separated by boundary BAR + >=900cy load latency. Bs[db] stage (W3/W4 of T)
// vs b1 reads (W1 of T): separated by MIDBAR + latency. vmcnt(4) at W4:
// newest 4 = B(T+2) stages -> A(T+1) and B(T+1) (issued last tile) landed.
// XOR swizzle byte^=(row&7)<<4 via pre-swizzled global source + swizzled
// ds_read (gload_lds dest stays linear).
template<int KTILES, bool ATOMIC>
__device__ __forceinline__ void gemm_body(
    const unsigned short* __restrict__ A, const unsigned short* __restrict__ W,
    float* __restrict__ C, int m0, int n0, int kbase, bool do_silu)
{
  __shared__ __align__(16) unsigned short As[2][2][128 * 64];  // [db][half]
  __shared__ __align__(16) unsigned short Bs[2][2][128 * 64];

  const int tid  = threadIdx.x;
  const int lane = tid & 63;
  const int wid  = tid >> 6;
  const int wr   = wid >> 2;          // 0..1  M-half of the wave
  const int wc   = wid & 3;           // 0..3  N-quarter of the wave
  const int fr   = lane & 15;
  const int fku  = lane >> 4;         // 0..3
  const int cxA  = fku * 16;          // byte col base within a 128B LDS row

  // staging: thread covers 2x16B of each 128x64 half-tile (16 KB).
  const int ob0 = tid * 16, ob1 = (512 + tid) * 16;
  const int r0 = ob0 >> 7, r1 = ob1 >> 7;                 // 0..63 / 64..127
  const int cb0 = (ob0 & 127) ^ ((r0 & 7) << 4);
  const int cb1 = (ob1 & 127) ^ ((r1 & 7) << 4);
  const unsigned short* A0 = A + (size_t)(m0 + r0) * HIDN + kbase + (cb0 >> 1);
  const unsigned short* A1 = A + (size_t)(m0 + r1) * HIDN + kbase + (cb1 >> 1);
  const unsigned short* W0 = W + (size_t)(n0 + r0) * HIDN + kbase + (cb0 >> 1);
  const unsigned short* W1 = W + (size_t)(n0 + r1) * HIDN + kbase + (cb1 >> 1);
  const int lo0 = ob0 >> 1, lo1 = ob1 >> 1;               // ushort offsets

  f32x4 acc[8][4];
#pragma unroll
  for (int mi = 0; mi < 8; ++mi)
#pragma unroll
    for (int ni = 0; ni < 4; ++ni) acc[mi][ni] = (f32x4){0.f, 0.f, 0.f, 0.f};

  auto stageA = [&](int t, int h, int db) {
    gload_lds16(A0 + (size_t)h * 128 * HIDN + t * 64, &As[db][h][lo0]);
    gload_lds16(A1 + (size_t)h * 128 * HIDN + t * 64, &As[db][h][lo1]);
  };
  auto stageB = [&](int t, int h, int db) {
    gload_lds16(W0 + (size_t)h * 128 * HIDN + t * 64, &Bs[db][h][lo0]);
    gload_lds16(W1 + (size_t)h * 128 * HIDN + t * 64, &Bs[db][h][lo1]);
  };
  auto readA = [&](bf16x8 (&a)[2][4], int db, int mh) {
#pragma unroll
    for (int kk = 0; kk < 2; ++kk)
#pragma unroll
      for (int mi = 0; mi < 4; ++mi) {
        int rr  = mh * 64 + mi * 16 + fr;
        int byo = rr * 128 + ((kk * 64 + cxA) ^ ((rr & 7) << 4));
        a[kk][mi] = *(const bf16x8*)((const char*)As[db][wr] + byo);
      }
  };
  auto readB = [&](bf16x8 (&b)[2][2], int db, int nh) {
#pragma unroll
    for (int kk = 0; kk < 2; ++kk)
#pragma unroll
      for (int ni = 0; ni < 2; ++ni) {
        int rr  = (wc & 1) * 64 + nh * 32 + ni * 16 + fr;
        int byo = rr * 128 + ((kk * 64 + cxA) ^ ((rr & 7) << 4));
        b[kk][ni] = *(const bf16x8*)((const char*)Bs[db][wc >> 1] + byo);
      }
  };
  auto quad = [&](bf16x8 (&a)[2][4], bf16x8 (&b)[2][2], int mh, int nh) {
#pragma unroll
    for (int kk = 0; kk < 2; ++kk)
#pragma unroll
      for (int mi = 0; mi < 4; ++mi)
#pragma unroll
        for (int ni = 0; ni < 2; ++ni)
          acc[mh * 4 + mi][nh * 2 + ni] = __builtin_amdgcn_mfma_f32_16x16x32_bf16(
              a[kk][mi], b[kk][ni], acc[mh * 4 + mi][nh * 2 + ni], 0, 0, 0);
  };

  // prologue: B(0), A(0) into slot 0; B(1) into slot 1. vmcnt(4) leaves the
  // two B(1) stage-pairs in flight, guarantees tile 0 fully staged.
  stageB(0, 0, 0); stageB(0, 1, 0);
  stageA(0, 0, 0); stageA(0, 1, 0);
  stageB(1, 0, 1); stageB(1, 1, 1);
  WAIT_VM4();
  BAR();

  bf16x8 a8[2][4], b0[2][2], b1[2][2];
  readA(a8, 0, 0);   // a0 of tile 0
  readB(b0, 0, 0);   // b0 of tile 0

  for (int T = 0; T < KTILES; ++T) {
    const int db  = T & 1;
    const int dbA = db ^ 1;
    const int tA  = (T + 1 < KTILES) ? T + 1 : T;   // tail: harmless re-stage
    const int tB  = (T + 2 < KTILES) ? T + 2 : T;
    // ---- W1 ----
    readB(b1, db, 1);
    stageA(tA, 0, dbA);
    __builtin_amdgcn_s_setprio(1);
    quad(a8, b0, 0, 0);
    __builtin_amdgcn_s_setprio(0);
    // ---- W2 ----
    stageA(tA, 1, dbA);
    __builtin_amdgcn_s_setprio(1);
    quad(a8, b1, 0, 1);
    __builtin_amdgcn_s_setprio(0);
    readA(a8, db, 1);          // a1 of T (reg reuse after Q2)
    BAR();                      // midbar: b-reads above, B-stage below
    // ---- W3 ----
    stageB(tB, 0, db);
    __builtin_amdgcn_s_setprio(1);
    quad(a8, b1, 1, 1);
    __builtin_amdgcn_s_setprio(0);
    // ---- W4 ----
    stageB(tB, 1, db);
    __builtin_amdgcn_s_setprio(1);
    quad(a8, b0, 1, 0);
    __builtin_amdgcn_s_setprio(0);
    WAIT_VM4();
    BAR();                      // boundary: publishes tile T+1
    readA(a8, dbA, 0);         // a0 of T+1 (garbage on last iter, unused)
    readB(b0, dbA, 0);         // b0 of T+1
  }
  WAIT_VM0();   // drain leftover (garbage) prefetch before epilogue

  const int orow = fku * 4;
#pragma unroll
  for (int mi = 0; mi < 8; ++mi)
#pragma unroll
    for (int ni = 0; ni < 4; ++ni)
#pragma unroll
      for (int r = 0; r < 4; ++r) {
        int row = m0 + wr * 128 + mi * 16 + orow + r;
        int col = n0 + wc * 64 + ni * 16 + fr;
        float v = acc[mi][ni][r];
        if (ATOMIC) {
          atomicAdd(&C[(size_t)row * HIDN + col], v);
        } else {
          if (do_silu) v = v / (1.f + __expf(-v));
          C[(size_t)row * HIDN + col] = v;
        }
      }
}

// k,v,r,g projections: grid 256 = 4z x 16nt x 4mt; full K=4096 (64 K-tiles).
__global__ __launch_bounds__(512, 2)
void gemm_main(const unsigned short* __restrict__ Aall,
               const unsigned short* __restrict__ Wall,
               float* __restrict__ Call, int silu_mask)
{
  const int bid  = blockIdx.x;
  const int xcd  = bid & 7;
  const int slot = bid >> 3;                 // 0..31
  const int nz   = xcd * 8 + (slot >> 2);    // 0..63
  const int mt   = slot & 3;
  const int z    = nz >> 4;
  const int nt   = nz & 15;
  gemm_body<64, false>(Aall + (size_t)z * S_LEN * HIDN,
                       Wall + (size_t)z * HIDN * HIDN,
                       Call + (size_t)z * S_LEN * HIDN,
                       mt * 256, nt * 256, 0, (silu_mask >> z) & 1);
}

// output projection: split-K x4, grid 256 = 8xcd x {nt-lo, ks(2b), mt(2b)}.
__global__ __launch_bounds__(512, 2)
void gemm_out(const unsigned short* __restrict__ A,
              const unsigned short* __restrict__ W,
              float* __restrict__ C)
{
  const int bid  = blockIdx.x;
  const int xcd  = bid & 7;
  const int slot = bid >> 3;                 // 0..31
  const int nt   = xcd * 2 + (slot & 1);     // 0..15
  const int ks   = (slot >> 1) & 3;          // 0..3
  const int mt   = (slot >> 3) & 3;          // 0..3
  gemm_body<16, true>(A, W, C, mt * 256, nt * 256, ks * (HIDN / 4), false);
}

// -------------------- recurrence pass 1: local chunk states ------------------
__global__ __launch_bounds__(64)
void rec_pass1(const float* __restrict__ kb, const float* __restrict__ vb,
               const float* __restrict__ time_decay, float* __restrict__ X)
{
  const int c = blockIdx.x, h = blockIdx.y, e = threadIdx.x;
  const float tde = __expf(-__expf(time_decay[h * 64 + e]));
  float td[64];
#pragma unroll
  for (int d = 0; d < 64; ++d) td[d] = __shfl(tde, d, 64);
  float st[64];
#pragma unroll
  for (int d = 0; d < 64; ++d) st[d] = 0.f;

  for (int t = c * CLEN; t < c * CLEN + CLEN; ++t) {
    const size_t off = (size_t)t * HIDN + h * 64;
    const float vl = vb[off + e];
    const float* __restrict__ krow = kb + off;   // uniform address over d
#pragma unroll
    for (int d = 0; d < 64; ++d)
      st[d] = fmaf(td[d], st[d], krow[d] * vl);
  }
#pragma unroll
  for (int d = 0; d < 64; ++d)
    X[(((size_t)c * NH + h) * 64 + d) * 64 + e] = st[d];
}

// ------------- recurrence pass 2: scan boundary states across chunks ---------
__global__ __launch_bounds__(64)
void rec_pass2(const float* __restrict__ time_decay,
               const float* __restrict__ X, float* __restrict__ Y)
{
  const int h = blockIdx.x, dq = blockIdx.y, e = threadIdx.x;
  float tdc[16];
#pragma unroll
  for (int i = 0; i < 16; ++i)
    tdc[i] = __expf(-(float)CLEN * __expf(time_decay[h * 64 + dq * 16 + i]));
  float acc[16];
#pragma unroll
  for (int i = 0; i < 16; ++i) acc[i] = 0.f;
  for (int c = 0; c < NCH; ++c) {
#pragma unroll
    for (int i = 0; i < 16; ++i) {
      size_t idx = (((size_t)c * NH + h) * 64 + dq * 16 + i) * 64 + e;
      Y[idx] = acc[i];
      acc[i] = fmaf(tdc[i], acc[i], X[idx]);
    }
  }
}

// ------- recurrence pass 3: outputs + fused GroupNorm + gate -> A2 (bf16) ----
__global__ __launch_bounds__(64)
void rec_pass3(const float* __restrict__ kb, const float* __restrict__ vb,
               const float* __restrict__ rb, const float* __restrict__ gb,
               const float* __restrict__ time_decay, const float* __restrict__ time_faaaa,
               const float* __restrict__ gnw, const float* __restrict__ gnb,
               const float* __restrict__ Y, unsigned short* __restrict__ A2)
{
  const int c = blockIdx.x, h = blockIdx.y, e = threadIdx.x;
  const float tde = __expf(-__expf(time_decay[h * 64 + e]));
  float td[64];
#pragma unroll
  for (int d = 0; d < 64; ++d) td[d] = __shfl(tde, d, 64);
  float st[64];
#pragma unroll
  for (int d = 0; d < 64; ++d)
    st[d] = Y[(((size_t)c * NH + h) * 64 + d) * 64 + e];

  const float tf_l  = time_faaaa[h * 64 + e];
  const float gnw_l = gnw[h * 64 + e];
  const float gnb_l = gnb[h * 64 + e];

  for (int t = c * CLEN; t < c * CLEN + CLEN; ++t) {
    const size_t off = (size_t)t * HIDN + h * 64;
    const float kl = kb[off + e], rl = rb[off + e];
    const float vl = vb[off + e], gl = gb[off + e];

    float Asum = rl * tf_l * kl;
#pragma unroll
    for (int i = 1; i < 64; i <<= 1) Asum += __shfl_xor(Asum, i, 64);

    const float* __restrict__ krow = kb + off;   // uniform address over d
    const float* __restrict__ rrow = rb + off;
    float dot = 0.f;
#pragma unroll
    for (int d = 0; d < 64; ++d) {
      dot   = fmaf(rrow[d], st[d], dot);                 // uses state_{t-1}
      st[d] = fmaf(td[d], st[d], krow[d] * vl);          // state_t
    }
    float o = fmaf(Asum, vl, dot);

    float s1 = o, s2 = o * o;
#pragma unroll
    for (int i = 1; i < 64; i <<= 1) {
      s1 += __shfl_xor(s1, i, 64);
      s2 += __shfl_xor(s2, i, 64);
    }
    float mean = s1 * (1.f / 64.f);
    float var  = s2 * (1.f / 64.f) - mean * mean;
    float xn   = (o - mean) * rsqrtf(var + 1e-5f);
    float yv   = xn * gnw_l + gnb_l;
    A2[off + e] = f2bf(gl * yv);
  }
}

// -----------------------------------------------------------------------------
extern "C" void kernel_launch(void* const* d_in, const int* in_sizes, int n_in,
                              void* d_out, int out_size, void* d_ws, size_t ws_size,
                              hipStream_t stream)
{
  const float* hidden     = (const float*)d_in[0];
  const float* w_key      = (const float*)d_in[1];
  const float* w_value    = (const float*)d_in[2];
  const float* w_recep    = (const float*)d_in[3];
  const float* w_gate     = (const float*)d_in[4];
  const float* w_output   = (const float*)d_in[5];
  const float* tmk        = (const float*)d_in[6];
  const float* tmv        = (const float*)d_in[7];
  const float* tmr        = (const float*)d_in[8];
  const float* tmg        = (const float*)d_in[9];
  const float* time_decay = (const float*)d_in[10];
  const float* time_faaaa = (const float*)d_in[11];
  const float* gnw        = (const float*)d_in[12];
  const float* gnb        = (const float*)d_in[13];
  float* out = (float*)d_out;

  char* ws = (char*)d_ws;
  // ws layout (bytes):
  //   wbf   bf16 [5][4096][4096]  @ 0          (167,772,160)  wk,wv,wr,wg,wo
  //     Y   f32  [32][64][64][64] @ 0          (33,554,432)   aliases wk+wv (dead after gemms)
  //   mixed bf16 [4][S][HID]      @ 167772160  (33,554,432)
  //     X   f32  [32][64][64][64] @ 167772160  aliases mixed  (dead after gemms)
  //   kvrg  f32  [4][S][HID]      @ 201326592  (67,108,864)
  //   A2    bf16 [S][HID]         @ 268435456  (8,388,608)    total 276.8 MB
  unsigned short* wbf   = (unsigned short*)(ws);
  float*          Y     = (float*)(ws);
  unsigned short* mixed = (unsigned short*)(ws + 167772160);
  float*          X     = (float*)(ws + 167772160);
  float*          kvrg  = (float*)(ws + 201326592);
  unsigned short* A2    = (unsigned short*)(ws + 268435456);

  const float* kb = kvrg + 0 * (size_t)S_LEN * HIDN;
  const float* vb = kvrg + 1 * (size_t)S_LEN * HIDN;
  const float* rb = kvrg + 2 * (size_t)S_LEN * HIDN;
  const float* gb = kvrg + 3 * (size_t)S_LEN * HIDN;

  wconv_kernel<<<dim3(HIDN * HIDN / 2048, 5), 256, 0, stream>>>(
      w_key, w_value, w_recep, w_gate, w_output, wbf);

  mix_kernel<<<dim3(S_LEN * HIDN / 256), 256, 0, stream>>>(hidden, tmk, tmv, tmr, tmg, mixed);

  // k,v,r,g = mixed[z] @ W[z]^T ; silu on z==3 (gate). 256 blocks, 512 thr.
  gemm_main<<<dim3(256), 512, 0, stream>>>(mixed, wbf, kvrg, 0x8);

  rec_pass1<<<dim3(NCH, NH), 64, 0, stream>>>(kb, vb, time_decay, X);
  rec_pass2<<<dim3(NH, 4), 64, 0, stream>>>(time_decay, X, Y);
  rec_pass3<<<dim3(NCH, NH), 64, 0, stream>>>(kb, vb, rb, gb, time_decay, time_faaaa,
                                              gnw, gnb, Y, A2);

  // out = (g * groupnorm(o)) @ w_output^T, split-K x4 with atomic epilogue.
  hipMemsetAsync(d_out, 0, (size_t)out_size * sizeof(float), stream);
  gemm_out<<<dim3(256), 512, 0, stream>>>(A2, wbf + 4 * (size_t)HIDN * HIDN, out);
}